// Round 5
// baseline (273.768 us; speedup 1.0000x reference)
//
#include <hip/hip_runtime.h>
#include <hip/hip_fp16.h>
#include <cstdint>
#include <cstddef>

// Problem constants: B=256, C=1, NMAX=256 -> N=65536 nodes, E=N*16=1048576,
// EMB=HID=128, decode K = NMAX = 256.
#define NN   65536
#define NE   1048576
#define FD   128
#define KDEC 256
#define NGRAPH 256

typedef __attribute__((ext_vector_type(8))) short s16x8;
typedef __attribute__((ext_vector_type(4))) float f32x4;

__device__ __forceinline__ ushort f2bf(float x) {
  uint u = __float_as_uint(x);
  uint r = (u + 0x7fffu + ((u >> 16) & 1u)) >> 16;  // RNE
  return (ushort)r;
}
__device__ __forceinline__ float bf2f(ushort h) {
  return __uint_as_float(((uint)h) << 16);
}

// ---------------- CSR build: histogram, scan (+dinv), scatter ----------------

__global__ __launch_bounds__(256) void k_hist(const int* __restrict__ edges,
                                              int* __restrict__ hist) {
  int i = blockIdx.x * 256 + threadIdx.x;
  if (i < NE) atomicAdd(&hist[edges[2 * i + 1]], 1);
}

__global__ __launch_bounds__(256) void k_blocksum(const int* __restrict__ hist,
                                                  int* __restrict__ bsum) {
  __shared__ int s[256];
  int t = threadIdx.x;
  s[t] = hist[blockIdx.x * 256 + t];
  __syncthreads();
  for (int st = 128; st > 0; st >>= 1) {
    if (t < st) s[t] += s[t + st];
    __syncthreads();
  }
  if (t == 0) bsum[blockIdx.x] = s[0];
}

__global__ __launch_bounds__(256) void k_scanb(int* __restrict__ bsum) {
  __shared__ int s[256];
  int t = threadIdx.x;
  int v = bsum[t];
  s[t] = v;
  __syncthreads();
  for (int off = 1; off < 256; off <<= 1) {
    int add = (t >= off) ? s[t - off] : 0;
    __syncthreads();
    s[t] += add;
    __syncthreads();
  }
  bsum[t] = s[t] - v;  // exclusive
}

__global__ __launch_bounds__(256) void k_scanfinal(const int* __restrict__ hist,
                                                   const int* __restrict__ bsum,
                                                   int* __restrict__ offs,
                                                   float* __restrict__ dinv) {
  __shared__ int s[256];
  int t = threadIdx.x, b = blockIdx.x;
  int v = hist[b * 256 + t];
  s[t] = v;
  __syncthreads();
  for (int off = 1; off < 256; off <<= 1) {
    int add = (t >= off) ? s[t - off] : 0;
    __syncthreads();
    s[t] += add;
    __syncthreads();
  }
  offs[b * 256 + t] = bsum[b] + s[t] - v;
  dinv[b * 256 + t] = rsqrtf((float)(v + 1));
}

// scatter: CSR-ordered packed (src<<16)|f16(coef), 4 B/edge
__global__ __launch_bounds__(256) void k_scatter(const int* __restrict__ edges,
                                                 const int* __restrict__ offs,
                                                 int* __restrict__ cnt,
                                                 const float* __restrict__ dinv,
                                                 uint* __restrict__ ec) {
  int i = blockIdx.x * 256 + threadIdx.x;
  if (i < NE) {
    int s = edges[2 * i];
    int d = edges[2 * i + 1];
    int pos = offs[d] + atomicAdd(&cnt[d], 1);
    __half hc = __float2half(dinv[s] * dinv[d]);
    ec[pos] = ((uint)s << 16) | (uint)__half_as_ushort(hc);
  }
}

// ---------------- W pre-fragmentation (split bf16, fragment-major), fused x3 ----
// index(k,c) = ((k/32)*8 + c/16)*64*8 + ((c&15) + 16*((k&31)>>3))*8 + (k&7)

__global__ __launch_bounds__(256) void k_prepw3(const float* __restrict__ Wd,
                                                const float* __restrict__ W1,
                                                const float* __restrict__ W2,
                                                ushort* __restrict__ wdh, ushort* __restrict__ wdl,
                                                ushort* __restrict__ w1h, ushort* __restrict__ w1l,
                                                ushort* __restrict__ w2h, ushort* __restrict__ w2l) {
  int b = blockIdx.x;
  const float* W;
  ushort *H, *L;
  int i;
  if (b < 128)      { W = Wd; H = wdh; L = wdl; i = b * 256 + threadIdx.x; }
  else if (b < 192) { W = W1; H = w1h; L = w1l; i = (b - 128) * 256 + threadIdx.x; }
  else              { W = W2; H = w2h; L = w2l; i = (b - 192) * 256 + threadIdx.x; }
  int k = i >> 7, c = i & 127;
  float w = W[i];
  ushort h = f2bf(w);
  ushort lo = f2bf(w - bf2f(h));
  size_t dst = ((size_t)((k >> 5) * 8 + (c >> 4)) * 64 +
                (size_t)((c & 15) + 16 * ((k & 31) >> 3))) * 8 + (k & 7);
  H[dst] = h;
  L[dst] = lo;
}

// ---------------- split-bf16 MFMA GEMM: Y[M,128] = X[M,K] @ W[K,128] (+bias) ----
// 256 threads = 4 waves; BM=128 (wave w owns rows [w*32, w*32+32) = 2 m-frags).
// ASPLIT: A pre-split bf16 hi/lo planes [M][K]; else fp32 A, split in regs.
// OUT=0: emit hi/lo bf16 planes [M][128]. OUT=1: emit slice-major bf16 [8][NN][16].

template <bool ASPLIT, int OUT>
__global__ __launch_bounds__(256) void k_gemm(const void* __restrict__ A0,
                                              const void* __restrict__ A1,
                                              const ushort* __restrict__ Whi,
                                              const ushort* __restrict__ Wlo,
                                              const float* __restrict__ bias,
                                              void* __restrict__ Y0,
                                              void* __restrict__ Y1, int K) {
  const int t = threadIdx.x;
  const int w = t >> 6;
  const int l = t & 63;
  const int lr = l & 15;   // row-in-frag (A) / col-in-frag (B,C)
  const int kg = l >> 4;   // k-group 0..3
  const int r0 = blockIdx.x * 128 + w * 32;

  f32x4 acc[2][8];
#pragma unroll
  for (int mb = 0; mb < 2; mb++)
#pragma unroll
    for (int nb = 0; nb < 8; nb++) acc[mb][nb] = (f32x4)0.f;

  for (int ks = 0; ks < K; ks += 32) {
    s16x8 ah[2], al[2];
    if (ASPLIT) {
#pragma unroll
      for (int mb = 0; mb < 2; mb++) {
        size_t base = (size_t)(r0 + mb * 16 + lr) * K + ks + kg * 8;
        ah[mb] = *(const s16x8*)((const ushort*)A0 + base);
        al[mb] = *(const s16x8*)((const ushort*)A1 + base);
      }
    } else {
#pragma unroll
      for (int mb = 0; mb < 2; mb++) {
        const float* xp = (const float*)A0 + (size_t)(r0 + mb * 16 + lr) * K + ks + kg * 8;
        f32x4 x0 = *(const f32x4*)xp;
        f32x4 x1 = *(const f32x4*)(xp + 4);
        float xv[8] = {x0.x, x0.y, x0.z, x0.w, x1.x, x1.y, x1.z, x1.w};
        union { ushort u[8]; s16x8 v; } H, L;
#pragma unroll
        for (int e = 0; e < 8; e++) {
          ushort h = f2bf(xv[e]);
          H.u[e] = h;
          L.u[e] = f2bf(xv[e] - bf2f(h));
        }
        ah[mb] = H.v;
        al[mb] = L.v;
      }
    }
    const size_t bbase = (size_t)(ks >> 5) * 4096 + (size_t)l * 8;
    s16x8 bh[8], bl[8];
#pragma unroll
    for (int nb = 0; nb < 8; nb++) {
      bh[nb] = *(const s16x8*)(Whi + bbase + nb * 512);
      bl[nb] = *(const s16x8*)(Wlo + bbase + nb * 512);
    }
#pragma unroll
    for (int mb = 0; mb < 2; mb++)
#pragma unroll
      for (int nb = 0; nb < 8; nb++) {
        acc[mb][nb] = __builtin_amdgcn_mfma_f32_16x16x32_bf16(ah[mb], bh[nb], acc[mb][nb], 0, 0, 0);
        acc[mb][nb] = __builtin_amdgcn_mfma_f32_16x16x32_bf16(ah[mb], bl[nb], acc[mb][nb], 0, 0, 0);
        acc[mb][nb] = __builtin_amdgcn_mfma_f32_16x16x32_bf16(al[mb], bh[nb], acc[mb][nb], 0, 0, 0);
      }
  }

  // epilogue: C/D col = lr (within frag), row = kg*4 + reg
#pragma unroll
  for (int nb = 0; nb < 8; nb++) {
    int col = nb * 16 + lr;
    float bv = bias ? bias[col] : 0.f;
#pragma unroll
    for (int mb = 0; mb < 2; mb++) {
#pragma unroll
      for (int r = 0; r < 4; r++) {
        size_t row = (size_t)(r0 + mb * 16 + kg * 4 + r);
        float v = acc[mb][nb][r] + bv;
        if (OUT == 0) {
          ushort hi = f2bf(v);
          ((ushort*)Y0)[row * FD + col] = hi;
          ((ushort*)Y1)[row * FD + col] = f2bf(v - bf2f(hi));
        } else {
          // slice-major [8][NN][16], slice = nb
          ((ushort*)Y0)[(size_t)nb * NN * 16 + row * 16 + lr] = f2bf(v);
        }
      }
    }
  }
}

// ---------------- GCN aggregation: slice-pinned table, 4-lanes-per-node --------
// h16s: [8][NN][16] bf16; slice = blockIdx&7 -> XCD-pinned (2 MB/slice resident
// in that XCD's L2; validated by round-3 FETCH drop). Block = 64 nodes of one
// slice; 4 lanes per node, lane owns 4 dims (ushort4). All 4 lanes read the
// same edge record (broadcast, L1-hot sequential CSR segment) -> NO shuffle
// reduction in the hot loop. 4-wide edge unroll for MLP.
// EMIT=0: write hi/lo bf16 planes. EMIT=1: fused segment-max pooling.

template <int EMIT>
__global__ __launch_bounds__(256) void k_agg(const ushort* __restrict__ h16s,
                                             const uint* __restrict__ ec,
                                             const int* __restrict__ offs,
                                             const int* __restrict__ hist,
                                             const float* __restrict__ dinv,
                                             const float* __restrict__ bias,
                                             ushort* __restrict__ yhi,
                                             ushort* __restrict__ ylo,
                                             float* __restrict__ pooled) {
  __shared__ int pmax[16];
  const int t = threadIdx.x;
  if (EMIT == 1) {
    if (t < 16) pmax[t] = 0;
    __syncthreads();
  }
  const int s = blockIdx.x & 7;
  const int n = (blockIdx.x >> 3) * 64 + (t >> 2);
  const int q = t & 3;
  const ushort* hs = h16s + (size_t)s * (NN * 16) + q * 4;

  const int start = offs[n];
  const int cnt = hist[n];

  float a0 = 0.f, a1 = 0.f, a2 = 0.f, a3 = 0.f;
  int e = 0;
  for (; e + 3 < cnt; e += 4) {
    uint r0 = ec[start + e];
    uint r1 = ec[start + e + 1];
    uint r2 = ec[start + e + 2];
    uint r3 = ec[start + e + 3];
    ushort4 v0 = *(const ushort4*)(hs + ((size_t)(r0 >> 16) << 4));
    ushort4 v1 = *(const ushort4*)(hs + ((size_t)(r1 >> 16) << 4));
    ushort4 v2 = *(const ushort4*)(hs + ((size_t)(r2 >> 16) << 4));
    ushort4 v3 = *(const ushort4*)(hs + ((size_t)(r3 >> 16) << 4));
    float c0 = __half2float(__ushort_as_half((ushort)(r0 & 0xffffu)));
    float c1 = __half2float(__ushort_as_half((ushort)(r1 & 0xffffu)));
    float c2 = __half2float(__ushort_as_half((ushort)(r2 & 0xffffu)));
    float c3 = __half2float(__ushort_as_half((ushort)(r3 & 0xffffu)));
    a0 = fmaf(c0, bf2f(v0.x), a0);
    a1 = fmaf(c0, bf2f(v0.y), a1);
    a2 = fmaf(c0, bf2f(v0.z), a2);
    a3 = fmaf(c0, bf2f(v0.w), a3);
    a0 = fmaf(c1, bf2f(v1.x), a0);
    a1 = fmaf(c1, bf2f(v1.y), a1);
    a2 = fmaf(c1, bf2f(v1.z), a2);
    a3 = fmaf(c1, bf2f(v1.w), a3);
    a0 = fmaf(c2, bf2f(v2.x), a0);
    a1 = fmaf(c2, bf2f(v2.y), a1);
    a2 = fmaf(c2, bf2f(v2.z), a2);
    a3 = fmaf(c2, bf2f(v2.w), a3);
    a0 = fmaf(c3, bf2f(v3.x), a0);
    a1 = fmaf(c3, bf2f(v3.y), a1);
    a2 = fmaf(c3, bf2f(v3.z), a2);
    a3 = fmaf(c3, bf2f(v3.w), a3);
  }
  for (; e < cnt; e++) {
    uint r = ec[start + e];
    ushort4 v = *(const ushort4*)(hs + ((size_t)(r >> 16) << 4));
    float c = __half2float(__ushort_as_half((ushort)(r & 0xffffu)));
    a0 = fmaf(c, bf2f(v.x), a0);
    a1 = fmaf(c, bf2f(v.y), a1);
    a2 = fmaf(c, bf2f(v.z), a2);
    a3 = fmaf(c, bf2f(v.w), a3);
  }

  // self term + bias + relu
  float dv = dinv[n];
  float dd = dv * dv;
  ushort4 vs = *(const ushort4*)(hs + ((size_t)n << 4));
  float4 bb = *(const float4*)(bias + s * 16 + q * 4);
  float o0 = fmaxf(a0 + bf2f(vs.x) * dd + bb.x, 0.f);
  float o1 = fmaxf(a1 + bf2f(vs.y) * dd + bb.y, 0.f);
  float o2 = fmaxf(a2 + bf2f(vs.z) * dd + bb.z, 0.f);
  float o3 = fmaxf(a3 + bf2f(vs.w) * dd + bb.w, 0.f);

  if (EMIT == 0) {
    ushort4 hi, lo;
    hi.x = f2bf(o0); lo.x = f2bf(o0 - bf2f(hi.x));
    hi.y = f2bf(o1); lo.y = f2bf(o1 - bf2f(hi.y));
    hi.z = f2bf(o2); lo.z = f2bf(o2 - bf2f(hi.z));
    hi.w = f2bf(o3); lo.w = f2bf(o3 - bf2f(hi.w));
    size_t base = (size_t)n * FD + s * 16 + q * 4;
    *(ushort4*)(yhi + base) = hi;
    *(ushort4*)(ylo + base) = lo;
  } else {
    // max over the wave's 16 nodes via xor-shuffles (strides 4..32), then LDS,
    // then one global atomicMax per dim per block.
#pragma unroll
    for (int m = 4; m <= 32; m <<= 1) {
      o0 = fmaxf(o0, __shfl_xor(o0, m));
      o1 = fmaxf(o1, __shfl_xor(o1, m));
      o2 = fmaxf(o2, __shfl_xor(o2, m));
      o3 = fmaxf(o3, __shfl_xor(o3, m));
    }
    if ((t & 63) < 4) {
      // relu>=0: int-compare == float-compare for non-negative floats
      atomicMax(&pmax[q * 4 + 0], __float_as_int(o0));
      atomicMax(&pmax[q * 4 + 1], __float_as_int(o1));
      atomicMax(&pmax[q * 4 + 2], __float_as_int(o2));
      atomicMax(&pmax[q * 4 + 3], __float_as_int(o3));
    }
    __syncthreads();
    if (t < 16) {
      int gr = blockIdx.x >> 5;  // 32 blocks (8 slices x 256 nodes) per graph
      atomicMax((int*)pooled + gr * FD + s * 16 + t, pmax[t]);
    }
  }
}

// ---------------- MLP head ----------------

__global__ __launch_bounds__(128) void k_mlp(const float* __restrict__ pooled,
                                             const float* __restrict__ Wp1,
                                             const float* __restrict__ bp1,
                                             const float* __restrict__ Wp2,
                                             const float* __restrict__ bp2,
                                             float* __restrict__ out) {
  __shared__ float row[128];
  __shared__ float red[128];
  int g = blockIdx.x, t = threadIdx.x;
  row[t] = pooled[g * FD + t];
  __syncthreads();
  float acc = bp1[t];
#pragma unroll 8
  for (int k = 0; k < 128; k++) acc = fmaf(row[k], Wp1[k * FD + t], acc);
  acc = fmaxf(acc, 0.f);
  red[t] = acc * Wp2[t];
  __syncthreads();
  for (int st = 64; st > 0; st >>= 1) {
    if (t < st) red[t] += red[t + st];
    __syncthreads();
  }
  if (t == 0) out[g] = red[0] + bp2[0];
}

// ---------------- launch ----------------

extern "C" void kernel_launch(void* const* d_in, const int* in_sizes, int n_in,
                              void* d_out, int out_size, void* d_ws, size_t ws_size,
                              hipStream_t stream) {
  (void)in_sizes; (void)n_in; (void)out_size; (void)ws_size;

  const float* adj  = (const float*)d_in[0];
  const int*   edges= (const int*)d_in[1];
  const float* Wdec = (const float*)d_in[3];
  const float* bdec = (const float*)d_in[4];
  const float* Wc1  = (const float*)d_in[5];
  const float* bc1  = (const float*)d_in[6];
  const float* Wc2  = (const float*)d_in[7];
  const float* bc2  = (const float*)d_in[8];
  const float* Wp1  = (const float*)d_in[9];
  const float* bp1  = (const float*)d_in[10];
  const float* Wp2  = (const float*)d_in[11];
  const float* bp2  = (const float*)d_in[12];
  float* out = (float*)d_out;

  char* ws = (char*)d_ws;
  size_t off = 0;
  auto alloc = [&](size_t bytes) -> void* {
    void* p = ws + off;
    off += (bytes + 255) & ~(size_t)255;
    return p;
  };
  ushort* x0hi = (ushort*)alloc((size_t)NN * FD * 2);  // 16 MB
  ushort* x0lo = (ushort*)alloc((size_t)NN * FD * 2);
  ushort* x1hi = (ushort*)alloc((size_t)NN * FD * 2);
  ushort* x1lo = (ushort*)alloc((size_t)NN * FD * 2);
  ushort* h16s = (ushort*)alloc((size_t)NN * FD * 2);  // slice-major [8][NN][16]
  // hist | cnt | pooled contiguous -> single memset
  int*    hist = (int*)alloc((size_t)NN * 4);
  int*    cnt  = (int*)alloc((size_t)NN * 4);
  float*  pooled = (float*)alloc((size_t)NGRAPH * FD * 4);
  int*    offs = (int*)alloc((size_t)NN * 4);
  int*    bsum = (int*)alloc(256 * 4);
  uint*   ec   = (uint*)alloc((size_t)NE * 4);         // 4 MB packed
  float*  dinv = (float*)alloc((size_t)NN * 4);
  ushort* wdh = (ushort*)alloc((size_t)KDEC * FD * 2);
  ushort* wdl = (ushort*)alloc((size_t)KDEC * FD * 2);
  ushort* w1h = (ushort*)alloc((size_t)FD * FD * 2);
  ushort* w1l = (ushort*)alloc((size_t)FD * FD * 2);
  ushort* w2h = (ushort*)alloc((size_t)FD * FD * 2);
  ushort* w2l = (ushort*)alloc((size_t)FD * FD * 2);

  // zero hist+cnt+pooled in one shot (contiguous, 256B-aligned chunks)
  hipMemsetAsync(hist, 0, (size_t)NN * 4 + (size_t)NN * 4 + (size_t)NGRAPH * FD * 4, stream);

  // CSR build (shared by both GCN layers)
  k_hist<<<NE / 256, 256, 0, stream>>>(edges, hist);
  k_blocksum<<<256, 256, 0, stream>>>(hist, bsum);
  k_scanb<<<1, 256, 0, stream>>>(bsum);
  k_scanfinal<<<256, 256, 0, stream>>>(hist, bsum, offs, dinv);
  k_scatter<<<NE / 256, 256, 0, stream>>>(edges, offs, cnt, dinv, ec);

  // W split+fragment (once; reused by all GEMM blocks)
  k_prepw3<<<256, 256, 0, stream>>>(Wdec, Wc1, Wc2, wdh, wdl, w1h, w1l, w2h, w2l);

  // x0 = adj @ Wdec + bdec  -> pre-split bf16 planes
  k_gemm<false, 0><<<NN / 128, 256, 0, stream>>>(adj, nullptr, wdh, wdl, bdec, x0hi, x0lo, KDEC);

  // layer 1: h1 = x0 @ Wc1 -> slice-major table ; x1 = relu(agg+self+bc1) -> planes
  k_gemm<true, 1><<<NN / 128, 256, 0, stream>>>(x0hi, x0lo, w1h, w1l, nullptr, h16s, nullptr, FD);
  k_agg<0><<<8 * (NN / 64), 256, 0, stream>>>(h16s, ec, offs, hist, dinv, bc1, x1hi, x1lo, nullptr);

  // layer 2: h2 = x1 @ Wc2 -> slice-major table ; pooled = segmax(relu(agg+self+bc2))
  k_gemm<true, 1><<<NN / 128, 256, 0, stream>>>(x1hi, x1lo, w2h, w2l, nullptr, h16s, nullptr, FD);
  k_agg<1><<<8 * (NN / 64), 256, 0, stream>>>(h16s, ec, offs, hist, dinv, bc2, nullptr, nullptr, pooled);

  // MLP head
  k_mlp<<<NGRAPH, 128, 0, stream>>>(pooled, Wp1, bp1, Wp2, bp2, out);
}

// Round 6
// 252.304 us; speedup vs baseline: 1.0851x; 1.0851x over previous
//
#include <hip/hip_runtime.h>
#include <hip/hip_fp16.h>
#include <cstdint>
#include <cstddef>

// Problem constants: B=256, C=1, NMAX=256 -> N=65536 nodes, E=N*16=1048576,
// EMB=HID=128, decode K = NMAX = 256.
#define NN   65536
#define NE   1048576
#define FD   128
#define KDEC 256
#define NGRAPH 256

typedef __attribute__((ext_vector_type(8))) short s16x8;
typedef __attribute__((ext_vector_type(4))) float f32x4;

__device__ __forceinline__ ushort f2bf(float x) {
  uint u = __float_as_uint(x);
  uint r = (u + 0x7fffu + ((u >> 16) & 1u)) >> 16;  // RNE
  return (ushort)r;
}
__device__ __forceinline__ float bf2f(ushort h) {
  return __uint_as_float(((uint)h) << 16);
}

// ---------------- CSR build ----------------

__global__ __launch_bounds__(256) void k_hist(const int* __restrict__ edges,
                                              int* __restrict__ hist) {
  int i = blockIdx.x * 256 + threadIdx.x;
  if (i < NE) atomicAdd(&hist[edges[2 * i + 1]], 1);
}

// W pre-fragmentation helper (split bf16, fragment-major):
// dst(k,c) = ((k/32)*8 + c/16)*512 + ((c&15) + 16*((k&31)>>3))*8 + (k&7)
__device__ __forceinline__ void prep_one(const float* __restrict__ W,
                                         ushort* __restrict__ H,
                                         ushort* __restrict__ L, int i) {
  int k = i >> 7, c = i & 127;
  float w = W[i];
  ushort h = f2bf(w);
  ushort lo = f2bf(w - bf2f(h));
  size_t dst = ((size_t)((k >> 5) * 8 + (c >> 4)) * 64 +
                (size_t)((c & 15) + 16 * ((k & 31) >> 3))) * 8 + (k & 7);
  H[dst] = h;
  L[dst] = lo;
}

// misc1: blocks 0-255 blocksum | 256-383 Wfused=Wdec@Wc1 (+bfused) | 384-447 prep Wc2
__global__ __launch_bounds__(256) void k_misc1(const int* __restrict__ hist,
                                               int* __restrict__ bsum,
                                               const float* __restrict__ Wdec,
                                               const float* __restrict__ Wc1,
                                               const float* __restrict__ bdec,
                                               float* __restrict__ wfused,
                                               float* __restrict__ bfused,
                                               const float* __restrict__ Wc2,
                                               ushort* __restrict__ w2h,
                                               ushort* __restrict__ w2l) {
  int b = blockIdx.x, t = threadIdx.x;
  if (b < 256) {
    __shared__ int s[256];
    s[t] = hist[b * 256 + t];
    __syncthreads();
    for (int st = 128; st > 0; st >>= 1) {
      if (t < st) s[t] += s[t + st];
      __syncthreads();
    }
    if (t == 0) bsum[b] = s[0];
  } else if (b < 384) {
    int i = (b - 256) * 256 + t;  // 0..32767
    int k = i >> 7, c = i & 127;
    float acc = 0.f;
#pragma unroll 8
    for (int j = 0; j < 128; j++) acc = fmaf(Wdec[k * FD + j], Wc1[j * FD + c], acc);
    wfused[i] = acc;
    if (b == 256 && t < 128) {
      float ba = 0.f;
      for (int j = 0; j < 128; j++) ba = fmaf(bdec[j], Wc1[j * FD + t], ba);
      bfused[t] = ba;
    }
  } else {
    int i = (b - 384) * 256 + t;  // 0..16383
    prep_one(Wc2, w2h, w2l, i);
  }
}

// misc2: blocks 0-255 scanfinal (scanb fused in-block) | 256-383 prep Wfused
__global__ __launch_bounds__(256) void k_misc2(const int* __restrict__ hist,
                                               const int* __restrict__ bsum,
                                               int* __restrict__ offs,
                                               float* __restrict__ dinv,
                                               const float* __restrict__ wfused,
                                               ushort* __restrict__ wfh,
                                               ushort* __restrict__ wfl) {
  int b = blockIdx.x, t = threadIdx.x;
  if (b < 256) {
    __shared__ int sb[256];
    __shared__ int s[256];
    sb[t] = bsum[t];
    int v = hist[b * 256 + t];
    s[t] = v;
    __syncthreads();
    // inclusive scan of both arrays (Hillis-Steele)
    for (int off = 1; off < 256; off <<= 1) {
      int addb = (t >= off) ? sb[t - off] : 0;
      int add = (t >= off) ? s[t - off] : 0;
      __syncthreads();
      sb[t] += addb;
      s[t] += add;
      __syncthreads();
    }
    int pb = (b > 0) ? sb[b - 1] : 0;
    offs[b * 256 + t] = pb + s[t] - v;
    dinv[b * 256 + t] = rsqrtf((float)(v + 1));
  } else {
    int i = (b - 256) * 256 + t;  // 0..32767
    prep_one(wfused, wfh, wfl, i);
  }
}

// scatter: CSR-ordered packed (src<<16)|f16(coef), 4 B/edge
__global__ __launch_bounds__(256) void k_scatter(const int* __restrict__ edges,
                                                 const int* __restrict__ offs,
                                                 int* __restrict__ cnt,
                                                 const float* __restrict__ dinv,
                                                 uint* __restrict__ ec) {
  int i = blockIdx.x * 256 + threadIdx.x;
  if (i < NE) {
    int s = edges[2 * i];
    int d = edges[2 * i + 1];
    int pos = offs[d] + atomicAdd(&cnt[d], 1);
    __half hc = __float2half(dinv[s] * dinv[d]);
    ec[pos] = ((uint)s << 16) | (uint)__half_as_ushort(hc);
  }
}

// ---------------- split-bf16 MFMA GEMM: Y[M,128] = X[M,K] @ W[K,128] (+bias) ----
// BM=64: 256 threads = 4 waves, wave = one 16-row m-frag (grid NN/64 = 1024 ->
// 4 blocks/CU for latency hiding). ASPLIT: A pre-split bf16 planes; else fp32 A.
// Output: row-major bf16 [M][128].

template <bool ASPLIT>
__global__ __launch_bounds__(256) void k_gemm(const void* __restrict__ A0,
                                              const void* __restrict__ A1,
                                              const ushort* __restrict__ Whi,
                                              const ushort* __restrict__ Wlo,
                                              const float* __restrict__ bias,
                                              ushort* __restrict__ Y, int K) {
  const int t = threadIdx.x;
  const int w = t >> 6;
  const int l = t & 63;
  const int lr = l & 15;   // row-in-frag (A) / col-in-frag (B,C)
  const int kg = l >> 4;   // k-group 0..3
  const int r0 = blockIdx.x * 64 + w * 16;

  f32x4 acc[8];
#pragma unroll
  for (int nb = 0; nb < 8; nb++) acc[nb] = (f32x4)0.f;

  for (int ks = 0; ks < K; ks += 32) {
    s16x8 ah, al;
    if (ASPLIT) {
      size_t base = (size_t)(r0 + lr) * K + ks + kg * 8;
      ah = *(const s16x8*)((const ushort*)A0 + base);
      al = *(const s16x8*)((const ushort*)A1 + base);
    } else {
      const float* xp = (const float*)A0 + (size_t)(r0 + lr) * K + ks + kg * 8;
      f32x4 x0 = *(const f32x4*)xp;
      f32x4 x1 = *(const f32x4*)(xp + 4);
      float xv[8] = {x0.x, x0.y, x0.z, x0.w, x1.x, x1.y, x1.z, x1.w};
      union { ushort u[8]; s16x8 v; } H, L;
#pragma unroll
      for (int e = 0; e < 8; e++) {
        ushort h = f2bf(xv[e]);
        H.u[e] = h;
        L.u[e] = f2bf(xv[e] - bf2f(h));
      }
      ah = H.v;
      al = L.v;
    }
    const size_t bbase = (size_t)(ks >> 5) * 4096 + (size_t)l * 8;
#pragma unroll
    for (int nb = 0; nb < 8; nb++) {
      s16x8 bh = *(const s16x8*)(Whi + bbase + nb * 512);
      s16x8 bl = *(const s16x8*)(Wlo + bbase + nb * 512);
      acc[nb] = __builtin_amdgcn_mfma_f32_16x16x32_bf16(ah, bh, acc[nb], 0, 0, 0);
      acc[nb] = __builtin_amdgcn_mfma_f32_16x16x32_bf16(ah, bl, acc[nb], 0, 0, 0);
      acc[nb] = __builtin_amdgcn_mfma_f32_16x16x32_bf16(al, bh, acc[nb], 0, 0, 0);
    }
  }

  // epilogue: C/D col = lr (within frag), row = kg*4 + reg
#pragma unroll
  for (int nb = 0; nb < 8; nb++) {
    int col = nb * 16 + lr;
    float bv = bias ? bias[col] : 0.f;
#pragma unroll
    for (int r = 0; r < 4; r++) {
      size_t row = (size_t)(r0 + kg * 4 + r);
      Y[row * FD + col] = f2bf(acc[nb][r] + bv);
    }
  }
}

// ---------------- GCN aggregation: wave-per-node, 4-deep gather pipeline --------
// h16: [NN][128] bf16. Wave = 1 node; lane l: edge parity half=l>>5,
// dims dl=(l&31)*4 (ushort4, halves gather different edges). 8 edges in flight
// per wave iter, 2 accumulator banks. Full 256-B rows -> 4 fully-used lines/edge,
// zero edge-loop divergence (proven 48.3 us structure, round 4).
// EMIT=0: write hi/lo bf16 planes. EMIT=1: fused segment-max pooling.

template <int EMIT>
__global__ __launch_bounds__(256) void k_agg(const ushort* __restrict__ h16,
                                             const uint* __restrict__ ec,
                                             const int* __restrict__ offs,
                                             const int* __restrict__ hist,
                                             const float* __restrict__ dinv,
                                             const float* __restrict__ bias,
                                             ushort* __restrict__ yhi,
                                             ushort* __restrict__ ylo,
                                             float* __restrict__ pooled) {
  __shared__ int pmax[128];
  const int t = threadIdx.x;
  if (EMIT == 1) {
    if (t < 128) pmax[t] = 0;
    __syncthreads();
  }
  const int n = blockIdx.x * 4 + (t >> 6);
  const int l = t & 63;
  const int half = l >> 5;
  const int dl = (l & 31) * 4;

  const int start = offs[n];
  const int cnt = hist[n];

  float a0 = 0.f, a1 = 0.f, a2 = 0.f, a3 = 0.f;
  float b0 = 0.f, b1 = 0.f, b2 = 0.f, b3 = 0.f;
  int i = half;
  for (; i + 6 < cnt; i += 8) {
    uint r0 = ec[start + i];
    uint r1 = ec[start + i + 2];
    uint r2 = ec[start + i + 4];
    uint r3 = ec[start + i + 6];
    ushort4 v0 = *(const ushort4*)(h16 + ((size_t)(r0 >> 16) << 7) + dl);
    ushort4 v1 = *(const ushort4*)(h16 + ((size_t)(r1 >> 16) << 7) + dl);
    ushort4 v2 = *(const ushort4*)(h16 + ((size_t)(r2 >> 16) << 7) + dl);
    ushort4 v3 = *(const ushort4*)(h16 + ((size_t)(r3 >> 16) << 7) + dl);
    float c0 = __half2float(__ushort_as_half((ushort)(r0 & 0xffffu)));
    float c1 = __half2float(__ushort_as_half((ushort)(r1 & 0xffffu)));
    float c2 = __half2float(__ushort_as_half((ushort)(r2 & 0xffffu)));
    float c3 = __half2float(__ushort_as_half((ushort)(r3 & 0xffffu)));
    a0 = fmaf(c0, bf2f(v0.x), a0);
    a1 = fmaf(c0, bf2f(v0.y), a1);
    a2 = fmaf(c0, bf2f(v0.z), a2);
    a3 = fmaf(c0, bf2f(v0.w), a3);
    b0 = fmaf(c1, bf2f(v1.x), b0);
    b1 = fmaf(c1, bf2f(v1.y), b1);
    b2 = fmaf(c1, bf2f(v1.z), b2);
    b3 = fmaf(c1, bf2f(v1.w), b3);
    a0 = fmaf(c2, bf2f(v2.x), a0);
    a1 = fmaf(c2, bf2f(v2.y), a1);
    a2 = fmaf(c2, bf2f(v2.z), a2);
    a3 = fmaf(c2, bf2f(v2.w), a3);
    b0 = fmaf(c3, bf2f(v3.x), b0);
    b1 = fmaf(c3, bf2f(v3.y), b1);
    b2 = fmaf(c3, bf2f(v3.z), b2);
    b3 = fmaf(c3, bf2f(v3.w), b3);
  }
  for (; i < cnt; i += 2) {
    uint r = ec[start + i];
    ushort4 v = *(const ushort4*)(h16 + ((size_t)(r >> 16) << 7) + dl);
    float c = __half2float(__ushort_as_half((ushort)(r & 0xffffu)));
    a0 = fmaf(c, bf2f(v.x), a0);
    a1 = fmaf(c, bf2f(v.y), a1);
    a2 = fmaf(c, bf2f(v.z), a2);
    a3 = fmaf(c, bf2f(v.w), a3);
  }
  a0 += b0; a1 += b1; a2 += b2; a3 += b3;
  a0 += __shfl_xor(a0, 32);
  a1 += __shfl_xor(a1, 32);
  a2 += __shfl_xor(a2, 32);
  a3 += __shfl_xor(a3, 32);

  if (l < 32) {
    float dv = dinv[n];
    float dd = dv * dv;
    ushort4 vs = *(const ushort4*)(h16 + ((size_t)n << 7) + dl);
    float4 bb = *(const float4*)(bias + dl);
    float o0 = fmaxf(a0 + bf2f(vs.x) * dd + bb.x, 0.f);
    float o1 = fmaxf(a1 + bf2f(vs.y) * dd + bb.y, 0.f);
    float o2 = fmaxf(a2 + bf2f(vs.z) * dd + bb.z, 0.f);
    float o3 = fmaxf(a3 + bf2f(vs.w) * dd + bb.w, 0.f);
    if (EMIT == 0) {
      ushort4 hi, lo;
      hi.x = f2bf(o0); lo.x = f2bf(o0 - bf2f(hi.x));
      hi.y = f2bf(o1); lo.y = f2bf(o1 - bf2f(hi.y));
      hi.z = f2bf(o2); lo.z = f2bf(o2 - bf2f(hi.z));
      hi.w = f2bf(o3); lo.w = f2bf(o3 - bf2f(hi.w));
      size_t base = (size_t)n * FD + dl;
      *(ushort4*)(yhi + base) = hi;
      *(ushort4*)(ylo + base) = lo;
    } else {
      // relu>=0: int-compare == float-compare for non-negative floats
      atomicMax(&pmax[dl + 0], __float_as_int(o0));
      atomicMax(&pmax[dl + 1], __float_as_int(o1));
      atomicMax(&pmax[dl + 2], __float_as_int(o2));
      atomicMax(&pmax[dl + 3], __float_as_int(o3));
    }
  }
  if (EMIT == 1) {
    __syncthreads();
    if (t < 128) {
      int gr = blockIdx.x >> 6;  // 64 blocks (256 nodes) per graph
      atomicMax((int*)pooled + gr * FD + t, pmax[t]);
    }
  }
}

// ---------------- MLP head ----------------

__global__ __launch_bounds__(128) void k_mlp(const float* __restrict__ pooled,
                                             const float* __restrict__ Wp1,
                                             const float* __restrict__ bp1,
                                             const float* __restrict__ Wp2,
                                             const float* __restrict__ bp2,
                                             float* __restrict__ out) {
  __shared__ float row[128];
  __shared__ float red[128];
  int g = blockIdx.x, t = threadIdx.x;
  row[t] = pooled[g * FD + t];
  __syncthreads();
  float acc = bp1[t];
#pragma unroll 8
  for (int k = 0; k < 128; k++) acc = fmaf(row[k], Wp1[k * FD + t], acc);
  acc = fmaxf(acc, 0.f);
  red[t] = acc * Wp2[t];
  __syncthreads();
  for (int st = 64; st > 0; st >>= 1) {
    if (t < st) red[t] += red[t + st];
    __syncthreads();
  }
  if (t == 0) out[g] = red[0] + bp2[0];
}

// ---------------- launch ----------------

extern "C" void kernel_launch(void* const* d_in, const int* in_sizes, int n_in,
                              void* d_out, int out_size, void* d_ws, size_t ws_size,
                              hipStream_t stream) {
  (void)in_sizes; (void)n_in; (void)out_size; (void)ws_size;

  const float* adj  = (const float*)d_in[0];
  const int*   edges= (const int*)d_in[1];
  const float* Wdec = (const float*)d_in[3];
  const float* bdec = (const float*)d_in[4];
  const float* Wc1  = (const float*)d_in[5];
  const float* bc1  = (const float*)d_in[6];
  const float* Wc2  = (const float*)d_in[7];
  const float* bc2  = (const float*)d_in[8];
  const float* Wp1  = (const float*)d_in[9];
  const float* bp1  = (const float*)d_in[10];
  const float* Wp2  = (const float*)d_in[11];
  const float* bp2  = (const float*)d_in[12];
  float* out = (float*)d_out;

  char* ws = (char*)d_ws;
  size_t off = 0;
  auto alloc = [&](size_t bytes) -> void* {
    void* p = ws + off;
    off += (bytes + 255) & ~(size_t)255;
    return p;
  };
  ushort* h16  = (ushort*)alloc((size_t)NN * FD * 2);  // 16 MB bf16 table
  ushort* x1hi = (ushort*)alloc((size_t)NN * FD * 2);
  ushort* x1lo = (ushort*)alloc((size_t)NN * FD * 2);
  // hist | cnt | pooled contiguous -> single memset
  int*    hist = (int*)alloc((size_t)NN * 4);
  int*    cnt  = (int*)alloc((size_t)NN * 4);
  float*  pooled = (float*)alloc((size_t)NGRAPH * FD * 4);
  int*    offs = (int*)alloc((size_t)NN * 4);
  int*    bsum = (int*)alloc(256 * 4);
  uint*   ec   = (uint*)alloc((size_t)NE * 4);         // 4 MB packed
  float*  dinv = (float*)alloc((size_t)NN * 4);
  float*  wfused = (float*)alloc((size_t)KDEC * FD * 4);  // Wdec@Wc1 fp32
  float*  bfused = (float*)alloc(FD * 4);
  ushort* wfh = (ushort*)alloc((size_t)KDEC * FD * 2);
  ushort* wfl = (ushort*)alloc((size_t)KDEC * FD * 2);
  ushort* w2h = (ushort*)alloc((size_t)FD * FD * 2);
  ushort* w2l = (ushort*)alloc((size_t)FD * FD * 2);

  hipMemsetAsync(hist, 0, (size_t)NN * 4 + (size_t)NN * 4 + (size_t)NGRAPH * FD * 4, stream);

  k_hist<<<NE / 256, 256, 0, stream>>>(edges, hist);
  // blocksum + Wfused=Wdec@Wc1 (+bfused) + prep(Wc2)
  k_misc1<<<448, 256, 0, stream>>>(hist, bsum, Wdec, Wc1, bdec, wfused, bfused,
                                   Wc2, w2h, w2l);
  // scanfinal (scanb fused) + dinv + prep(Wfused)
  k_misc2<<<384, 256, 0, stream>>>(hist, bsum, offs, dinv, wfused, wfh, wfl);
  k_scatter<<<NE / 256, 256, 0, stream>>>(edges, offs, cnt, dinv, ec);

  // h1 = adj @ Wfused + bfused  (decode+c1 folded) -> bf16 table
  k_gemm<false><<<NN / 64, 256, 0, stream>>>(adj, nullptr, wfh, wfl, bfused, h16, KDEC);

  // x1 = relu(agg(h1)+self+bc1) -> hi/lo planes
  k_agg<0><<<NN / 4, 256, 0, stream>>>(h16, ec, offs, hist, dinv, bc1, x1hi, x1lo, nullptr);

  // h2 = x1 @ Wc2 -> bf16 table
  k_gemm<true><<<NN / 64, 256, 0, stream>>>(x1hi, x1lo, w2h, w2l, nullptr, h16, FD);

  // pooled = segmax(relu(agg(h2)+self+bc2)) fused
  k_agg<1><<<NN / 4, 256, 0, stream>>>(h16, ec, offs, hist, dinv, bc2, nullptr, nullptr, pooled);

  // MLP head
  k_mlp<<<NGRAPH, 128, 0, stream>>>(pooled, Wp1, bp1, Wp2, bp2, out);
}